// Round 3
// baseline (71.571 us; speedup 1.0000x reference)
//
#include <hip/hip_runtime.h>

// Bidirectional minGRU scan, linear-domain.
// x: (16, 512, 4096) f32.  out: (16, 256, 4096) f32.
// Row r = b*256 + c.  c<128: forward scan on h=x[b,c,:], g=x[b,c+128,:].
// c>=128: backward scan on h=x[b,256+j,:], g=x[b,384+j,:], j=c-128, with the
// output written at the same (reversed) time index == flip(scan(flip)).
//
// Per block (256 threads = 4 waves): each thread owns 16 contiguous scan steps.
// (c_t, v_t) = (sigmoid(-g), sigmoid(g)*h'); compose 16 steps locally to (C,V);
// wave-inclusive scan of (C,V) via __shfl_up (no barriers); one LDS stage for
// the 4 wave aggregates (single barrier); replay chunk from incoming state.

#define T_LEN 4096
#define CHUNK 16
#define NTHR 256

typedef float f32x4 __attribute__((ext_vector_type(4)));

__global__ __launch_bounds__(NTHR) void mingru_bidir_kernel(
    const float* __restrict__ x, float* __restrict__ out) {
  const int row = blockIdx.x;          // [0, 16*256)
  const int b   = row >> 8;
  const int c   = row & 255;
  const int tid = threadIdx.x;
  const int lane = tid & 63;
  const int wid  = tid >> 6;
  const bool bwd = (c >= 128);
  const int j = c & 127;

  const float* __restrict__ hptr =
      x + ((size_t)b * 512 + (bwd ? 256 : 0) + j) * T_LEN;
  const float* __restrict__ gptr =
      x + ((size_t)b * 512 + (bwd ? 384 : 128) + j) * T_LEN;
  float* __restrict__ optr = out + ((size_t)b * 256 + c) * T_LEN;

  // fwd: chunk covers t in [16*tid, 16*tid+15], scan order = increasing t.
  // bwd: scan steps s in [16*tid, 16*tid+15] map to t = 4095-s.
  const int t0 = bwd ? (T_LEN - CHUNK - (tid << 4)) : (tid << 4);

  float cc[CHUNK], vv[CHUNK];  // per-step (coeff, value), increasing-t order

  #pragma unroll
  for (int q = 0; q < 4; ++q) {
    const f32x4 h4 =
        __builtin_nontemporal_load(reinterpret_cast<const f32x4*>(hptr + t0 + 4 * q));
    const f32x4 g4 =
        __builtin_nontemporal_load(reinterpret_cast<const f32x4*>(gptr + t0 + 4 * q));
    #pragma unroll
    for (int r = 0; r < 4; ++r) {
      const int e = 4 * q + r;
      const float h = h4[r];
      const float g = g4[r];
      // h' = copysign(max(|h|, EPS), h)  (h==0 -> +EPS, matches reference)
      const float ah = fmaxf(fabsf(h), 1e-6f);
      const float hp = (h < 0.0f) ? -ah : ah;
      // sigmoid(g) via stable form + fast rcp; sigmoid(-g) = 1 - sigmoid(g)
      const float eg  = __expf(-fabsf(g));
      const float inv = __builtin_amdgcn_rcpf(1.0f + eg);
      const float sg  = (g >= 0.0f) ? inv : eg * inv;  // sigmoid(g)
      cc[e] = 1.0f - sg;
      vv[e] = sg * hp;
    }
  }

  // For backward rows, flip register arrays into scan order (uniform branch,
  // constant indices only -> stays in registers).
  if (bwd) {
    #pragma unroll
    for (int e = 0; e < CHUNK / 2; ++e) {
      float t1 = cc[e]; cc[e] = cc[CHUNK - 1 - e]; cc[CHUNK - 1 - e] = t1;
      float t2 = vv[e]; vv[e] = vv[CHUNK - 1 - e]; vv[CHUNK - 1 - e] = t2;
    }
  }

  // Local composition: after this thread's 16 steps, state = C*x_in + V.
  float C = cc[0], V = vv[0];
  #pragma unroll
  for (int e = 1; e < CHUNK; ++e) {
    V = cc[e] * V + vv[e];
    C = C * cc[e];
  }

  // Wave-inclusive scan of (C,V) over 64 lanes, no barriers.
  #pragma unroll
  for (int off = 1; off < 64; off <<= 1) {
    const float pc = __shfl_up(C, off);
    const float pv = __shfl_up(V, off);
    if (lane >= off) {
      V = C * pv + V;
      C = C * pc;
    }
  }

  // Cross-wave stage: 4 wave aggregates through LDS, one barrier.
  __shared__ float sC[4], sV[4];
  if (lane == 63) { sC[wid] = C; sV[wid] = V; }
  __syncthreads();
  float acc = 0.0f;  // state after all previous waves (initial state = 0)
  for (int w = 0; w < wid; ++w) acc = sC[w] * acc + sV[w];

  // Incoming state for this thread = inclusive(prev thread) applied to acc.
  const float pC = __shfl_up(C, 1);
  const float pV = __shfl_up(V, 1);
  const float incoming = (lane == 0) ? acc : pC * acc + pV;

  // Replay chunk from incoming state; vv becomes the outputs.
  float st = incoming;
  #pragma unroll
  for (int e = 0; e < CHUNK; ++e) {
    st = cc[e] * st + vv[e];
    vv[e] = st;
  }

  // Back to increasing-t order for stores.
  if (bwd) {
    #pragma unroll
    for (int e = 0; e < CHUNK / 2; ++e) {
      float t2 = vv[e]; vv[e] = vv[CHUNK - 1 - e]; vv[CHUNK - 1 - e] = t2;
    }
  }

  #pragma unroll
  for (int q = 0; q < 4; ++q) {
    const f32x4 o4 = {vv[4 * q], vv[4 * q + 1], vv[4 * q + 2], vv[4 * q + 3]};
    __builtin_nontemporal_store(o4, reinterpret_cast<f32x4*>(optr + t0 + 4 * q));
  }
}

extern "C" void kernel_launch(void* const* d_in, const int* in_sizes, int n_in,
                              void* d_out, int out_size, void* d_ws, size_t ws_size,
                              hipStream_t stream) {
  const float* x = (const float*)d_in[0];
  float* out = (float*)d_out;
  const int rows = 16 * 256;  // one block per output row
  mingru_bidir_kernel<<<rows, NTHR, 0, stream>>>(x, out);
}

// Round 4
// 39.266 us; speedup vs baseline: 1.8227x; 1.8227x over previous
//
#include <hip/hip_runtime.h>

// Bidirectional minGRU scan, linear-domain.
// x: (16, 512, 4096) f32.  out: (16, 256, 4096) f32.
// Row r = b*256 + c.  c<128: forward scan on h=x[b,c,:], g=x[b,c+128,:].
// c>=128: backward scan on h=x[b,256+j,:], g=x[b,384+j,:], j=c-128, with the
// output written at the same (reversed) time index == flip(scan(flip)).
//
// Per block (256 threads = 4 waves): each thread owns 16 contiguous scan steps.
// (c_t, v_t) = (sigmoid(-g), sigmoid(g)*h'); compose 16 steps locally to (C,V);
// wave-inclusive scan of (C,V) via __shfl_up (no barriers); one LDS stage for
// the 4 wave aggregates (single barrier); replay chunk from incoming state.
//
// NOTE: no nontemporal loads/stores — R3 showed `nt` partial-line writes
// (16B/lane at 64B lane stride) bypass L2 merging -> 1.45x write amplification.

#define T_LEN 4096
#define CHUNK 16
#define NTHR 256

__global__ __launch_bounds__(NTHR) void mingru_bidir_kernel(
    const float* __restrict__ x, float* __restrict__ out) {
  const int row = blockIdx.x;          // [0, 16*256)
  const int b   = row >> 8;
  const int c   = row & 255;
  const int tid = threadIdx.x;
  const int lane = tid & 63;
  const int wid  = tid >> 6;
  const bool bwd = (c >= 128);
  const int j = c & 127;

  const float* __restrict__ hptr =
      x + ((size_t)b * 512 + (bwd ? 256 : 0) + j) * T_LEN;
  const float* __restrict__ gptr =
      x + ((size_t)b * 512 + (bwd ? 384 : 128) + j) * T_LEN;
  float* __restrict__ optr = out + ((size_t)b * 256 + c) * T_LEN;

  // fwd: chunk covers t in [16*tid, 16*tid+15], scan order = increasing t.
  // bwd: scan steps s in [16*tid, 16*tid+15] map to t = 4095-s.
  const int t0 = bwd ? (T_LEN - CHUNK - (tid << 4)) : (tid << 4);

  float cc[CHUNK], vv[CHUNK];  // per-step (coeff, value), increasing-t order

  #pragma unroll
  for (int q = 0; q < 4; ++q) {
    const float4 h4 = *reinterpret_cast<const float4*>(hptr + t0 + 4 * q);
    const float4 g4 = *reinterpret_cast<const float4*>(gptr + t0 + 4 * q);
    const float hs[4] = {h4.x, h4.y, h4.z, h4.w};
    const float gs[4] = {g4.x, g4.y, g4.z, g4.w};
    #pragma unroll
    for (int r = 0; r < 4; ++r) {
      const int e = 4 * q + r;
      const float h = hs[r];
      const float g = gs[r];
      // h' = copysign(max(|h|, EPS), h)  (h==0 -> +EPS, matches reference)
      const float ah = fmaxf(fabsf(h), 1e-6f);
      const float hp = (h < 0.0f) ? -ah : ah;
      // sigmoid(g) via stable form + fast rcp; sigmoid(-g) = 1 - sigmoid(g)
      const float eg  = __expf(-fabsf(g));
      const float inv = __builtin_amdgcn_rcpf(1.0f + eg);
      const float sg  = (g >= 0.0f) ? inv : eg * inv;  // sigmoid(g)
      cc[e] = 1.0f - sg;
      vv[e] = sg * hp;
    }
  }

  // For backward rows, flip register arrays into scan order (uniform branch,
  // constant indices only -> stays in registers).
  if (bwd) {
    #pragma unroll
    for (int e = 0; e < CHUNK / 2; ++e) {
      float t1 = cc[e]; cc[e] = cc[CHUNK - 1 - e]; cc[CHUNK - 1 - e] = t1;
      float t2 = vv[e]; vv[e] = vv[CHUNK - 1 - e]; vv[CHUNK - 1 - e] = t2;
    }
  }

  // Local composition: after this thread's 16 steps, state = C*x_in + V.
  float C = cc[0], V = vv[0];
  #pragma unroll
  for (int e = 1; e < CHUNK; ++e) {
    V = cc[e] * V + vv[e];
    C = C * cc[e];
  }

  // Wave-inclusive scan of (C,V) over 64 lanes, no barriers.
  #pragma unroll
  for (int off = 1; off < 64; off <<= 1) {
    const float pc = __shfl_up(C, off);
    const float pv = __shfl_up(V, off);
    if (lane >= off) {
      V = C * pv + V;
      C = C * pc;
    }
  }

  // Cross-wave stage: 4 wave aggregates through LDS, one barrier.
  __shared__ float sC[4], sV[4];
  if (lane == 63) { sC[wid] = C; sV[wid] = V; }
  __syncthreads();
  float acc = 0.0f;  // state after all previous waves (initial state = 0)
  for (int w = 0; w < wid; ++w) acc = sC[w] * acc + sV[w];

  // Incoming state for this thread = inclusive(prev thread) applied to acc.
  const float pC = __shfl_up(C, 1);
  const float pV = __shfl_up(V, 1);
  const float incoming = (lane == 0) ? acc : pC * acc + pV;

  // Replay chunk from incoming state; vv becomes the outputs.
  float st = incoming;
  #pragma unroll
  for (int e = 0; e < CHUNK; ++e) {
    st = cc[e] * st + vv[e];
    vv[e] = st;
  }

  // Back to increasing-t order for stores.
  if (bwd) {
    #pragma unroll
    for (int e = 0; e < CHUNK / 2; ++e) {
      float t2 = vv[e]; vv[e] = vv[CHUNK - 1 - e]; vv[CHUNK - 1 - e] = t2;
    }
  }

  #pragma unroll
  for (int q = 0; q < 4; ++q) {
    *reinterpret_cast<float4*>(optr + t0 + 4 * q) =
        make_float4(vv[4 * q], vv[4 * q + 1], vv[4 * q + 2], vv[4 * q + 3]);
  }
}

extern "C" void kernel_launch(void* const* d_in, const int* in_sizes, int n_in,
                              void* d_out, int out_size, void* d_ws, size_t ws_size,
                              hipStream_t stream) {
  const float* x = (const float*)d_in[0];
  float* out = (float*)d_out;
  const int rows = 16 * 256;  // one block per output row
  mingru_bidir_kernel<<<rows, NTHR, 0, stream>>>(x, out);
}

// Round 5
// 34.565 us; speedup vs baseline: 2.0706x; 1.1360x over previous
//
#include <hip/hip_runtime.h>

// Bidirectional minGRU scan, linear-domain.
// x: (16, 512, 4096) f32.  out: (16, 256, 4096) f32.
// Row r = b*256 + c.  c<128: forward scan on h=x[b,c,:], g=x[b,c+128,:].
// c>=128: backward scan on h=x[b,256+j,:], g=x[b,384+j,:], j=c-128, with the
// output written at the same (reversed) time index == flip(scan(flip)).
//
// Per block (256 threads = 4 waves): each thread owns 16 contiguous scan steps.
// (c_t, v_t) = (sigmoid(-g), sigmoid(g)*h'); compose locally; wave shfl scan;
// one LDS stage for the 4 wave aggregates; replay chunk from incoming state.
//
// Stores go through LDS so each wave's global_store_dwordx4 covers 1024
// CONTIGUOUS bytes (full 128B lines) -> avoids L2 write-allocate line fetch
// that partial-line (16B/lane @ 64B stride) stores incur (~67MB hidden reads).
// LDS: 20-word stride per thread (pad 4) to reduce bank conflicts; 20480B
// exactly -> 8 blocks/CU. Wave aggregates live in pad holes.

#define T_LEN 4096
#define CHUNK 16
#define NTHR 256

__global__ __launch_bounds__(NTHR) void mingru_bidir_kernel(
    const float* __restrict__ x, float* __restrict__ out) {
  const int row = blockIdx.x;          // [0, 16*256)
  const int b   = row >> 8;
  const int c   = row & 255;
  const int tid = threadIdx.x;
  const int lane = tid & 63;
  const int wid  = tid >> 6;
  const bool bwd = (c >= 128);
  const int j = c & 127;

  const float* __restrict__ hptr =
      x + ((size_t)b * 512 + (bwd ? 256 : 0) + j) * T_LEN;
  const float* __restrict__ gptr =
      x + ((size_t)b * 512 + (bwd ? 384 : 128) + j) * T_LEN;
  float* __restrict__ optr = out + ((size_t)b * 256 + c) * T_LEN;

  // fwd: chunk covers t in [16*tid, 16*tid+15], scan order = increasing t.
  // bwd: scan steps s in [16*tid, 16*tid+15] map to t = 4095-s.
  const int t0 = bwd ? (T_LEN - CHUNK - (tid << 4)) : (tid << 4);

  float cc[CHUNK], vv[CHUNK];  // per-step (coeff, value), increasing-t order

  #pragma unroll
  for (int q = 0; q < 4; ++q) {
    const float4 h4 = *reinterpret_cast<const float4*>(hptr + t0 + 4 * q);
    const float4 g4 = *reinterpret_cast<const float4*>(gptr + t0 + 4 * q);
    const float hs[4] = {h4.x, h4.y, h4.z, h4.w};
    const float gs[4] = {g4.x, g4.y, g4.z, g4.w};
    #pragma unroll
    for (int r = 0; r < 4; ++r) {
      const int e = 4 * q + r;
      const float h = hs[r];
      const float g = gs[r];
      // h' = copysign(max(|h|, EPS), h)  (h==0 -> +EPS, matches reference)
      const float ah = fmaxf(fabsf(h), 1e-6f);
      const float hp = (h < 0.0f) ? -ah : ah;
      // sigmoid(g) via stable form + fast rcp; sigmoid(-g) = 1 - sigmoid(g)
      const float eg  = __expf(-fabsf(g));
      const float inv = __builtin_amdgcn_rcpf(1.0f + eg);
      const float sg  = (g >= 0.0f) ? inv : eg * inv;  // sigmoid(g)
      cc[e] = 1.0f - sg;
      vv[e] = sg * hp;
    }
  }

  // For backward rows, flip register arrays into scan order (uniform branch,
  // constant indices only -> stays in registers).
  if (bwd) {
    #pragma unroll
    for (int e = 0; e < CHUNK / 2; ++e) {
      float t1 = cc[e]; cc[e] = cc[CHUNK - 1 - e]; cc[CHUNK - 1 - e] = t1;
      float t2 = vv[e]; vv[e] = vv[CHUNK - 1 - e]; vv[CHUNK - 1 - e] = t2;
    }
  }

  // Local composition: after this thread's 16 steps, state = C*x_in + V.
  float C = cc[0], V = vv[0];
  #pragma unroll
  for (int e = 1; e < CHUNK; ++e) {
    V = cc[e] * V + vv[e];
    C = C * cc[e];
  }

  // Wave-inclusive scan of (C,V) over 64 lanes, no barriers.
  #pragma unroll
  for (int off = 1; off < 64; off <<= 1) {
    const float pc = __shfl_up(C, off);
    const float pv = __shfl_up(V, off);
    if (lane >= off) {
      V = C * pv + V;
      C = C * pc;
    }
  }

  // LDS: 256 threads x 20 words (16 data + 4 pad) = 20480 B exactly.
  // Wave-aggregate scalars live in pad holes: words 16..19 (sC), 36..39 (sV).
  __shared__ float lds[NTHR * 20];
  float* sC = lds + 16;
  float* sV = lds + 36;

  if (lane == 63) { sC[wid] = C; sV[wid] = V; }
  __syncthreads();
  float acc = 0.0f;  // state after all previous waves (initial state = 0)
  for (int w = 0; w < wid; ++w) acc = sC[w] * acc + sV[w];

  // Incoming state for this thread = inclusive(prev thread) applied to acc.
  const float pC = __shfl_up(C, 1);
  const float pV = __shfl_up(V, 1);
  const float incoming = (lane == 0) ? acc : pC * acc + pV;

  // Replay chunk from incoming state; vv becomes the outputs.
  float st = incoming;
  #pragma unroll
  for (int e = 0; e < CHUNK; ++e) {
    st = cc[e] * st + vv[e];
    vv[e] = st;
  }

  // Back to increasing-t order.
  if (bwd) {
    #pragma unroll
    for (int e = 0; e < CHUNK / 2; ++e) {
      float t2 = vv[e]; vv[e] = vv[CHUNK - 1 - e]; vv[CHUNK - 1 - e] = t2;
    }
  }

  // Logical chunk index within the row (bwd rows own chunk 255-tid).
  const int jj = bwd ? (NTHR - 1 - tid) : tid;

  __syncthreads();  // everyone done reading sC/sV before pads' neighbors fly
  #pragma unroll
  for (int q = 0; q < 4; ++q) {
    *reinterpret_cast<float4*>(&lds[20 * jj + 4 * q]) =
        make_float4(vv[4 * q], vv[4 * q + 1], vv[4 * q + 2], vv[4 * q + 3]);
  }
  __syncthreads();

  // Dense stores: instruction q, thread tid -> out[q*1024 + 4*tid + k].
  // Each wave covers 1024 contiguous bytes per instruction (full lines).
  #pragma unroll
  for (int q = 0; q < 4; ++q) {
    const float4 o4 = *reinterpret_cast<const float4*>(
        &lds[1280 * q + 20 * (tid >> 2) + 4 * (tid & 3)]);
    *reinterpret_cast<float4*>(optr + 1024 * q + 4 * tid) = o4;
  }
}

extern "C" void kernel_launch(void* const* d_in, const int* in_sizes, int n_in,
                              void* d_out, int out_size, void* d_ws, size_t ws_size,
                              hipStream_t stream) {
  const float* x = (const float*)d_in[0];
  float* out = (float*)d_out;
  const int rows = 16 * 256;  // one block per output row
  mingru_bidir_kernel<<<rows, NTHR, 0, stream>>>(x, out);
}